// Round 3
// baseline (230.639 us; speedup 1.0000x reference)
//
#include <hip/hip_runtime.h>

#define IMG   256
#define IMG2  65536
#define NB    64
#define NB2   128

// Block-range layout in the fused grid (all blocks are 256 threads):
//   [0, 2048)      crops S=8  (g=32): src = t>>5, ci = t&31
//   [2048, 3072)   crops S=16 (g=16): src = t>>4, ci = t&15
//   [3072, 3584)   crops S=32 (g=8):  src = t>>3, ci = t&7
//   [3584, 19968)  label: b = t>>8, u = t&255
#define NBLK_C8   2048
#define NBLK_C16  1024
#define NBLK_C32  512
#define NBLK_LBL  16384
#define NBLK_ALL  (NBLK_C8 + NBLK_C16 + NBLK_C32 + NBLK_LBL)

// ---------------------------------------------------------------------------
// crops: one block per (src image, cell-row ci). Key identity: both the
// unshifted (A, batch src) and shifted (B, batch src+64) cells are contiguous
// S x S image blocks at rowbase/colbase = max(c*S-4, 0). Two coalesced float4
// sweeps over the stripe: (1) min/max stats (shuffle + tiny-LDS reduce),
// (2) re-read (L1/L2-hot) + normalize + coalesced float4 store. No LDS tile.
// Threads: w = tid>>6 picks row r = w+4k; lane l = tid&63 covers col 4l of
// the cell-row (cell cj = l/(S/4), offset o = 4*(l%(S/4))).
// ---------------------------------------------------------------------------
template <int S>
__device__ __forceinline__ void crops_cell_row(
    const float* __restrict__ img,
    const float* __restrict__ heat,
    float* __restrict__ out,
    int src, int ci,
    float (*s_red)[32][4],   // [4][32][4]
    float (*s_fin)[4]) {     // [32][4]
    constexpr int G   = IMG / S;
    constexpr int L   = (S == 8) ? 3 : (S == 16) ? 4 : 5;
    constexpr int CPL = S / 4;            // float4 lanes per cell per row

    const int tid = threadIdx.x;
    const int w   = tid >> 6;
    const int l   = tid & 63;
    const int cj  = l >> (L - 2);
    const int o   = (l & (CPL - 1)) * 4;

    const int rA   = ci * S;
    const int rB   = (ci == 0) ? 0 : rA - 4;
    const int colA = cj * S + o;                          // also the output col
    const int colB = ((cj == 0) ? 0 : cj * S - 4) + o;

    const float* __restrict__ sp = img + (size_t)src * IMG2;

    float mnA = 3.4e38f, mxA = -3.4e38f, mnB = 3.4e38f, mxB = -3.4e38f;
#pragma unroll
    for (int k = 0; k < S / 4; ++k) {
        const int r = w + 4 * k;
        const float4 a = *(const float4*)(sp + (rA + r) * IMG + colA);
        const float4 bq = *(const float4*)(sp + (rB + r) * IMG + colB);
        mnA = fminf(mnA, fminf(fminf(a.x, a.y), fminf(a.z, a.w)));
        mxA = fmaxf(mxA, fmaxf(fmaxf(a.x, a.y), fmaxf(a.z, a.w)));
        mnB = fminf(mnB, fminf(fminf(bq.x, bq.y), fminf(bq.z, bq.w)));
        mxB = fmaxf(mxB, fmaxf(fmaxf(bq.x, bq.y), fmaxf(bq.z, bq.w)));
    }
    // reduce across the CPL lanes of one cell (same w)
#pragma unroll
    for (int off = 1; off < CPL; off <<= 1) {
        mnA = fminf(mnA, __shfl_xor(mnA, off, 64));
        mxA = fmaxf(mxA, __shfl_xor(mxA, off, 64));
        mnB = fminf(mnB, __shfl_xor(mnB, off, 64));
        mxB = fmaxf(mxB, __shfl_xor(mxB, off, 64));
    }
    if ((l & (CPL - 1)) == 0) {
        float* p = &s_red[w][cj][0];
        p[0] = mnA; p[1] = mxA; p[2] = mnB; p[3] = mxB;
    }
    __syncthreads();
    if (tid < G) {
        float a0 = 3.4e38f, a1 = -3.4e38f, b0 = 3.4e38f, b1 = -3.4e38f;
#pragma unroll
        for (int ww = 0; ww < 4; ++ww) {
            a0 = fminf(a0, s_red[ww][tid][0]);
            a1 = fmaxf(a1, s_red[ww][tid][1]);
            b0 = fminf(b0, s_red[ww][tid][2]);
            b1 = fmaxf(b1, s_red[ww][tid][3]);
        }
        const float hA = heat[(size_t)src * G * G + ci * G + tid];
        const float hB = heat[(size_t)(src + NB) * G * G + ci * G + tid];
        s_fin[tid][0] = a0;
        s_fin[tid][1] = (hA > 0.5f ? 1.0f : 0.0f) / (a1 - a0 + 1e-5f);
        s_fin[tid][2] = b0;
        s_fin[tid][3] = (hB > 0.5f ? 1.0f : 0.0f) / (b1 - b0 + 1e-5f);
    }
    __syncthreads();
    const float fmnA = s_fin[cj][0], finvA = s_fin[cj][1];
    const float fmnB = s_fin[cj][2], finvB = s_fin[cj][3];

    float* __restrict__ dA = out + (size_t)src * IMG2;
    float* __restrict__ dB = out + (size_t)(src + NB) * IMG2;
#pragma unroll
    for (int k = 0; k < S / 4; ++k) {
        const int r = w + 4 * k;
        const float4 a = *(const float4*)(sp + (rA + r) * IMG + colA);
        const float4 bq = *(const float4*)(sp + (rB + r) * IMG + colB);
        float4 oa, ob;
        oa.x = (a.x - fmnA) * finvA;  oa.y = (a.y - fmnA) * finvA;
        oa.z = (a.z - fmnA) * finvA;  oa.w = (a.w - fmnA) * finvA;
        ob.x = (bq.x - fmnB) * finvB; ob.y = (bq.y - fmnB) * finvB;
        ob.z = (bq.z - fmnB) * finvB; ob.w = (bq.w - fmnB) * finvB;
        *(float4*)(dA + (rA + r) * IMG + colA) = oa;
        *(float4*)(dB + (rA + r) * IMG + colA) = ob;
    }
}

// ---------------------------------------------------------------------------
// label: one thread per output pixel (b, u, v); u block-uniform. All loads
// unconditional, gated by 0/1 masks. Fast path for u in [32,251].
// ---------------------------------------------------------------------------
__device__ __forceinline__ void label_pixel_row(
    const float* __restrict__ heat8,
    const float* __restrict__ heat16,
    const float* __restrict__ heat32,
    const float* __restrict__ seg8,
    const float* __restrict__ seg16,
    const float* __restrict__ seg32,
    float* __restrict__ out,
    int b, int u) {
    const int v = threadIdx.x;
    float num = 0.0f, den = 0.0f;

    if (u >= 32 && u <= 251) {
        const int i1 = u + 4;
        const int j1 = min(v + 4, 255);
#define SCALE_FAST(heat, seg, g, l, s)                                        \
        {                                                                     \
            const float* __restrict__ h1 = heat + b * (g * g);                \
            const float* __restrict__ h2 = heat + (NB + b) * (g * g);         \
            const float* __restrict__ s1 = seg + b * IMG2;                    \
            const float* __restrict__ s2 = seg + (NB + b) * IMG2;             \
            const float hd  = h1[(u >> l) * g + (v >> l)];                    \
            const float sd  = s1[u * IMG + v];                                \
            const float hg0 = h2[(i1 >> l) * g + (v >> l)];                   \
            const float hg1 = h2[(i1 >> l) * g + (j1 >> l)];                  \
            const float sg0 = s2[i1 * IMG + v];                               \
            const float sg1 = s2[i1 * IMG + j1];                              \
            const float md = (hd > 0.5f) ? 1.0f : 0.0f;                       \
            const float m0 = (v < (s) && hg0 > 0.5f) ? 1.0f : 0.0f;           \
            const float m1 = (v >= (s) - 4 && v <= 251 && hg1 > 0.5f)         \
                                 ? 1.0f : 0.0f;                               \
            num = fmaf(md, sd, num);                                          \
            num = fmaf(m0, sg0, num);                                         \
            num = fmaf(m1, sg1, num);                                         \
            den += md + m0 + m1;                                              \
        }
        SCALE_FAST(heat32, seg32, 32, 3, 8)
        SCALE_FAST(heat16, seg16, 16, 4, 16)
        SCALE_FAST(heat8,  seg8,  8,  5, 32)
#undef SCALE_FAST
    } else {
        const int i0 = u, i1 = min(u + 4, 255);
        const int j0 = v, j1 = min(v + 4, 255);
#define SCALE_GEN(heat, seg, g, l, s)                                         \
        {                                                                     \
            const float* __restrict__ h1 = heat + b * (g * g);                \
            const float* __restrict__ h2 = heat + (NB + b) * (g * g);         \
            const float* __restrict__ s1 = seg + b * IMG2;                    \
            const float* __restrict__ s2 = seg + (NB + b) * IMG2;             \
            const float miA = (u < (s)) ? 1.0f : 0.0f;                        \
            const float miB = (u >= (s) - 4 && u <= 251) ? 1.0f : 0.0f;       \
            const float mjA = (v < (s)) ? 1.0f : 0.0f;                        \
            const float mjB = (v >= (s) - 4 && v <= 251) ? 1.0f : 0.0f;       \
            const float hd  = h1[(u >> l) * g + (v >> l)];                    \
            const float sd  = s1[u * IMG + v];                                \
            const float h00 = h2[(i0 >> l) * g + (j0 >> l)];                  \
            const float h01 = h2[(i0 >> l) * g + (j1 >> l)];                  \
            const float h10 = h2[(i1 >> l) * g + (j0 >> l)];                  \
            const float h11 = h2[(i1 >> l) * g + (j1 >> l)];                  \
            const float s00 = s2[i0 * IMG + j0];                              \
            const float s01 = s2[i0 * IMG + j1];                              \
            const float s10 = s2[i1 * IMG + j0];                              \
            const float s11 = s2[i1 * IMG + j1];                              \
            const float md  = (hd > 0.5f) ? 1.0f : 0.0f;                      \
            const float m00 = (h00 > 0.5f) ? miA * mjA : 0.0f;                \
            const float m01 = (h01 > 0.5f) ? miA * mjB : 0.0f;                \
            const float m10 = (h10 > 0.5f) ? miB * mjA : 0.0f;                \
            const float m11 = (h11 > 0.5f) ? miB * mjB : 0.0f;                \
            num = fmaf(md, sd, num);                                          \
            num = fmaf(m00, s00, num);                                        \
            num = fmaf(m01, s01, num);                                        \
            num = fmaf(m10, s10, num);                                        \
            num = fmaf(m11, s11, num);                                        \
            den += md + m00 + m01 + m10 + m11;                                \
        }
        SCALE_GEN(heat32, seg32, 32, 3, 8)
        SCALE_GEN(heat16, seg16, 16, 4, 16)
        SCALE_GEN(heat8,  seg8,  8,  5, 32)
#undef SCALE_GEN
    }

    out[(size_t)b * IMG2 + u * IMG + v] = num / (den + 1e-10f);
}

// ---------------------------------------------------------------------------
// fused kernel: one dispatch for all three crops scales + label.
// ---------------------------------------------------------------------------
__global__ __launch_bounds__(256) void fused_kernel(
    const float* __restrict__ img,
    const float* __restrict__ heat8,
    const float* __restrict__ heat16,
    const float* __restrict__ heat32,
    const float* __restrict__ seg8,
    const float* __restrict__ seg16,
    const float* __restrict__ seg32,
    float* __restrict__ out) {
    __shared__ float s_red[4][32][4];
    __shared__ float s_fin[32][4];

    float* crops32 = out;                           // (128,1,256,256) s=8
    float* crops16 = out + (size_t)NB2 * IMG2;      // s=16
    float* crops8  = out + (size_t)2 * NB2 * IMG2;  // s=32
    float* label   = out + (size_t)3 * NB2 * IMG2;  // (64,1,256,256)

    const int bid = blockIdx.x;
    if (bid < NBLK_C8) {
        crops_cell_row<8>(img, heat32, crops32, bid >> 5, bid & 31, s_red, s_fin);
    } else if (bid < NBLK_C8 + NBLK_C16) {
        const int t = bid - NBLK_C8;
        crops_cell_row<16>(img, heat16, crops16, t >> 4, t & 15, s_red, s_fin);
    } else if (bid < NBLK_C8 + NBLK_C16 + NBLK_C32) {
        const int t = bid - (NBLK_C8 + NBLK_C16);
        crops_cell_row<32>(img, heat8, crops8, t >> 3, t & 7, s_red, s_fin);
    } else {
        const int t = bid - (NBLK_C8 + NBLK_C16 + NBLK_C32);
        label_pixel_row(heat8, heat16, heat32, seg8, seg16, seg32, label,
                        t >> 8, t & 255);
    }
}

extern "C" void kernel_launch(void* const* d_in, const int* in_sizes, int n_in,
                              void* d_out, int out_size, void* d_ws, size_t ws_size,
                              hipStream_t stream) {
    const float* img    = (const float*)d_in[0];
    const float* heat8  = (const float*)d_in[1];
    const float* heat16 = (const float*)d_in[2];
    const float* heat32 = (const float*)d_in[3];
    const float* seg8   = (const float*)d_in[4];
    const float* seg16  = (const float*)d_in[5];
    const float* seg32  = (const float*)d_in[6];

    fused_kernel<<<dim3(NBLK_ALL), 256, 0, stream>>>(
        img, heat8, heat16, heat32, seg8, seg16, seg32, (float*)d_out);
}

// Round 4
// 221.450 us; speedup vs baseline: 1.0415x; 1.0415x over previous
//
#include <hip/hip_runtime.h>

#define IMG   256
#define IMG2  65536
#define NB    64
#define NB2   128

// Block-range layout (all blocks 256 threads):
//   [0, 2048)      crops S=8  (g=32): src = t>>5, ci = t&31
//   [2048, 3072)   crops S=16 (g=16): src = t>>4, ci = t&15
//   [3072, 3584)   crops S=32 (g=8):  src = t>>3, ci = t&7
//   [3584, 7680)   label: b = t>>6, row-group = t&63 (4 rows, one per wave)
#define NBLK_C8   2048
#define NBLK_C16  1024
#define NBLK_C32  512
#define NBLK_LBL  4096
#define NBLK_ALL  (NBLK_C8 + NBLK_C16 + NBLK_C32 + NBLK_LBL)

// ---------------------------------------------------------------------------
// crops: one block per (src image, cell-row ci). Both the unshifted (A) and
// shifted (B) cells are contiguous S x S image blocks at base max(c*S-4,0).
// Sweep 1: float4 min/max stats (shuffle + tiny-LDS reduce).
// Sweep 2: re-read (cache-hot) + normalize + float4 stores for both outputs.
// ---------------------------------------------------------------------------
template <int S>
__device__ __forceinline__ void crops_cell_row(
    const float* __restrict__ img,
    const float* __restrict__ heat,
    float* __restrict__ out,
    int src, int ci,
    float (*s_red)[32][4],
    float (*s_fin)[4]) {
    constexpr int G   = IMG / S;
    constexpr int L   = (S == 8) ? 3 : (S == 16) ? 4 : 5;
    constexpr int CPL = S / 4;

    const int tid = threadIdx.x;
    const int w   = tid >> 6;
    const int l   = tid & 63;
    const int cj  = l >> (L - 2);
    const int o   = (l & (CPL - 1)) * 4;

    const int rA   = ci * S;
    const int rB   = (ci == 0) ? 0 : rA - 4;
    const int colA = cj * S + o;
    const int colB = ((cj == 0) ? 0 : cj * S - 4) + o;

    const float* __restrict__ sp = img + (size_t)src * IMG2;

    float mnA = 3.4e38f, mxA = -3.4e38f, mnB = 3.4e38f, mxB = -3.4e38f;
#pragma unroll
    for (int k = 0; k < S / 4; ++k) {
        const int r = w + 4 * k;
        const float4 a  = *(const float4*)(sp + (rA + r) * IMG + colA);
        const float4 bq = *(const float4*)(sp + (rB + r) * IMG + colB);
        mnA = fminf(mnA, fminf(fminf(a.x, a.y), fminf(a.z, a.w)));
        mxA = fmaxf(mxA, fmaxf(fmaxf(a.x, a.y), fmaxf(a.z, a.w)));
        mnB = fminf(mnB, fminf(fminf(bq.x, bq.y), fminf(bq.z, bq.w)));
        mxB = fmaxf(mxB, fmaxf(fmaxf(bq.x, bq.y), fmaxf(bq.z, bq.w)));
    }
#pragma unroll
    for (int off = 1; off < CPL; off <<= 1) {
        mnA = fminf(mnA, __shfl_xor(mnA, off, 64));
        mxA = fmaxf(mxA, __shfl_xor(mxA, off, 64));
        mnB = fminf(mnB, __shfl_xor(mnB, off, 64));
        mxB = fmaxf(mxB, __shfl_xor(mxB, off, 64));
    }
    if ((l & (CPL - 1)) == 0) {
        float* p = &s_red[w][cj][0];
        p[0] = mnA; p[1] = mxA; p[2] = mnB; p[3] = mxB;
    }
    __syncthreads();
    if (tid < G) {
        float a0 = 3.4e38f, a1 = -3.4e38f, b0 = 3.4e38f, b1 = -3.4e38f;
#pragma unroll
        for (int ww = 0; ww < 4; ++ww) {
            a0 = fminf(a0, s_red[ww][tid][0]);
            a1 = fmaxf(a1, s_red[ww][tid][1]);
            b0 = fminf(b0, s_red[ww][tid][2]);
            b1 = fmaxf(b1, s_red[ww][tid][3]);
        }
        const float hA = heat[(size_t)src * G * G + ci * G + tid];
        const float hB = heat[(size_t)(src + NB) * G * G + ci * G + tid];
        s_fin[tid][0] = a0;
        s_fin[tid][1] = (hA > 0.5f ? 1.0f : 0.0f) / (a1 - a0 + 1e-5f);
        s_fin[tid][2] = b0;
        s_fin[tid][3] = (hB > 0.5f ? 1.0f : 0.0f) / (b1 - b0 + 1e-5f);
    }
    __syncthreads();
    const float fmnA = s_fin[cj][0], finvA = s_fin[cj][1];
    const float fmnB = s_fin[cj][2], finvB = s_fin[cj][3];

    float* __restrict__ dA = out + (size_t)src * IMG2;
    float* __restrict__ dB = out + (size_t)(src + NB) * IMG2;
#pragma unroll
    for (int k = 0; k < S / 4; ++k) {
        const int r = w + 4 * k;
        const float4 a  = *(const float4*)(sp + (rA + r) * IMG + colA);
        const float4 bq = *(const float4*)(sp + (rB + r) * IMG + colB);
        float4 oa, ob;
        oa.x = (a.x - fmnA) * finvA;  oa.y = (a.y - fmnA) * finvA;
        oa.z = (a.z - fmnA) * finvA;  oa.w = (a.w - fmnA) * finvA;
        ob.x = (bq.x - fmnB) * finvB; ob.y = (bq.y - fmnB) * finvB;
        ob.z = (bq.z - fmnB) * finvB; ob.w = (bq.w - fmnB) * finvB;
        *(float4*)(dA + (rA + r) * IMG + colA) = oa;
        *(float4*)(dB + (rA + r) * IMG + colA) = ob;
    }
}

// ---------------------------------------------------------------------------
// label v3: one wave per row, 4 px per lane, float4 loads/stores. The +4
// column shift is an overlapping float4 load at min(v0+4,252) (16B-aligned;
// clamped lanes are fully masked). Pixels v0..v0+3 always share a heat cell
// (v0 multiple of 4, min cell width 8), so heat reads are scalar per lane.
// ---------------------------------------------------------------------------
__device__ __forceinline__ void label_rows(
    const float* __restrict__ heat8,
    const float* __restrict__ heat16,
    const float* __restrict__ heat32,
    const float* __restrict__ seg8,
    const float* __restrict__ seg16,
    const float* __restrict__ seg32,
    float* __restrict__ out,
    int b, int u0) {
    const int wave = threadIdx.x >> 6;
    const int lane = threadIdx.x & 63;
    const int u    = u0 + wave;
    const int v0   = lane << 2;
    const int vs   = min(v0 + 4, 252);   // shifted-load base, clamped

    float nu[4] = {0.f, 0.f, 0.f, 0.f};
    float de[4] = {0.f, 0.f, 0.f, 0.f};

    if (u0 >= 32 && u0 <= 248) {
        // fast: only preimage row i = u+4 exists for every scale
        const int i1 = u + 4;
#define SCALE_F(heat, seg, g, l, s)                                           \
        {                                                                     \
            const float* __restrict__ h1 = heat + b * (g * g);                \
            const float* __restrict__ h2 = heat + (NB + b) * (g * g);         \
            const float* __restrict__ r1 = seg + (size_t)b * IMG2 + u * IMG;  \
            const float* __restrict__ r2 =                                    \
                seg + (size_t)(NB + b) * IMG2 + i1 * IMG;                     \
            const float4 sd  = *(const float4*)(r1 + v0);                     \
            const float4 sg0 = *(const float4*)(r2 + v0);                     \
            const float4 sg1 = *(const float4*)(r2 + vs);                     \
            const float hd  = h1[(u >> l) * g + (v0 >> l)];                   \
            const float hg0 = h2[(i1 >> l) * g + (v0 >> l)];                  \
            const float hg1 = h2[(i1 >> l) * g + (vs >> l)];                  \
            const float md = (hd > 0.5f) ? 1.0f : 0.0f;                       \
            const float g0 = (hg0 > 0.5f) ? 1.0f : 0.0f;                      \
            const float g1 = (hg1 > 0.5f) ? 1.0f : 0.0f;                      \
            _Pragma("unroll")                                                 \
            for (int c = 0; c < 4; ++c) {                                     \
                const int v = v0 + c;                                         \
                const float m0 = (v < (s)) ? g0 : 0.0f;                       \
                const float m1 = (v >= (s) - 4 && v <= 251) ? g1 : 0.0f;      \
                float x = ((const float*)&sd)[c] * md;                        \
                x = fmaf(m0, ((const float*)&sg0)[c], x);                     \
                x = fmaf(m1, ((const float*)&sg1)[c], x);                     \
                nu[c] += x;                                                   \
                de[c] += md + m0 + m1;                                        \
            }                                                                 \
        }
        SCALE_F(heat32, seg32, 32, 3, 8)
        SCALE_F(heat16, seg16, 16, 4, 16)
        SCALE_F(heat8,  seg8,  8,  5, 32)
#undef SCALE_F
    } else {
        // generic: full 2x2 preimage with masks
        const int i0  = u;
        const int i1c = min(u + 4, 255);
#define SCALE_G(heat, seg, g, l, s)                                           \
        {                                                                     \
            const float* __restrict__ h1 = heat + b * (g * g);                \
            const float* __restrict__ h2 = heat + (NB + b) * (g * g);         \
            const float* __restrict__ r1 = seg + (size_t)b * IMG2 + u * IMG;  \
            const float* __restrict__ ra =                                    \
                seg + (size_t)(NB + b) * IMG2 + i0 * IMG;                     \
            const float* __restrict__ rb =                                    \
                seg + (size_t)(NB + b) * IMG2 + i1c * IMG;                    \
            const float4 sd  = *(const float4*)(r1 + v0);                     \
            const float4 a0q = *(const float4*)(ra + v0);                     \
            const float4 a1q = *(const float4*)(ra + vs);                     \
            const float4 b0q = *(const float4*)(rb + v0);                     \
            const float4 b1q = *(const float4*)(rb + vs);                     \
            const float hd  = h1[(u >> l) * g + (v0 >> l)];                   \
            const float hA0 = h2[(i0 >> l) * g + (v0 >> l)];                  \
            const float hA1 = h2[(i0 >> l) * g + (vs >> l)];                  \
            const float hB0 = h2[(i1c >> l) * g + (v0 >> l)];                 \
            const float hB1 = h2[(i1c >> l) * g + (vs >> l)];                 \
            const float miA = (u < (s)) ? 1.0f : 0.0f;                        \
            const float miB = (u >= (s) - 4 && u <= 251) ? 1.0f : 0.0f;       \
            const float md  = (hd > 0.5f) ? 1.0f : 0.0f;                      \
            const float gA0 = miA * ((hA0 > 0.5f) ? 1.0f : 0.0f);             \
            const float gA1 = miA * ((hA1 > 0.5f) ? 1.0f : 0.0f);             \
            const float gB0 = miB * ((hB0 > 0.5f) ? 1.0f : 0.0f);             \
            const float gB1 = miB * ((hB1 > 0.5f) ? 1.0f : 0.0f);             \
            _Pragma("unroll")                                                 \
            for (int c = 0; c < 4; ++c) {                                     \
                const int v = v0 + c;                                         \
                const float mj0 = (v < (s)) ? 1.0f : 0.0f;                    \
                const float mj1 = (v >= (s) - 4 && v <= 251) ? 1.0f : 0.0f;   \
                const float w00 = gA0 * mj0, w01 = gA1 * mj1;                 \
                const float w10 = gB0 * mj0, w11 = gB1 * mj1;                 \
                float x = ((const float*)&sd)[c] * md;                        \
                x = fmaf(w00, ((const float*)&a0q)[c], x);                    \
                x = fmaf(w01, ((const float*)&a1q)[c], x);                    \
                x = fmaf(w10, ((const float*)&b0q)[c], x);                    \
                x = fmaf(w11, ((const float*)&b1q)[c], x);                    \
                nu[c] += x;                                                   \
                de[c] += md + w00 + w01 + w10 + w11;                          \
            }                                                                 \
        }
        SCALE_G(heat32, seg32, 32, 3, 8)
        SCALE_G(heat16, seg16, 16, 4, 16)
        SCALE_G(heat8,  seg8,  8,  5, 32)
#undef SCALE_G
    }

    float4 o;
    o.x = nu[0] / (de[0] + 1e-10f);
    o.y = nu[1] / (de[1] + 1e-10f);
    o.z = nu[2] / (de[2] + 1e-10f);
    o.w = nu[3] / (de[3] + 1e-10f);
    *(float4*)(out + (size_t)b * IMG2 + u * IMG + v0) = o;
}

__global__ __launch_bounds__(256) void fused_kernel(
    const float* __restrict__ img,
    const float* __restrict__ heat8,
    const float* __restrict__ heat16,
    const float* __restrict__ heat32,
    const float* __restrict__ seg8,
    const float* __restrict__ seg16,
    const float* __restrict__ seg32,
    float* __restrict__ out) {
    __shared__ float s_red[4][32][4];
    __shared__ float s_fin[32][4];

    float* crops32 = out;                           // (128,1,256,256) s=8
    float* crops16 = out + (size_t)NB2 * IMG2;      // s=16
    float* crops8  = out + (size_t)2 * NB2 * IMG2;  // s=32
    float* label   = out + (size_t)3 * NB2 * IMG2;  // (64,1,256,256)

    const int bid = blockIdx.x;
    if (bid < NBLK_C8) {
        crops_cell_row<8>(img, heat32, crops32, bid >> 5, bid & 31, s_red, s_fin);
    } else if (bid < NBLK_C8 + NBLK_C16) {
        const int t = bid - NBLK_C8;
        crops_cell_row<16>(img, heat16, crops16, t >> 4, t & 15, s_red, s_fin);
    } else if (bid < NBLK_C8 + NBLK_C16 + NBLK_C32) {
        const int t = bid - (NBLK_C8 + NBLK_C16);
        crops_cell_row<32>(img, heat8, crops8, t >> 3, t & 7, s_red, s_fin);
    } else {
        const int t = bid - (NBLK_C8 + NBLK_C16 + NBLK_C32);
        label_rows(heat8, heat16, heat32, seg8, seg16, seg32, label,
                   t >> 6, (t & 63) << 2);
    }
}

extern "C" void kernel_launch(void* const* d_in, const int* in_sizes, int n_in,
                              void* d_out, int out_size, void* d_ws, size_t ws_size,
                              hipStream_t stream) {
    const float* img    = (const float*)d_in[0];
    const float* heat8  = (const float*)d_in[1];
    const float* heat16 = (const float*)d_in[2];
    const float* heat32 = (const float*)d_in[3];
    const float* seg8   = (const float*)d_in[4];
    const float* seg16  = (const float*)d_in[5];
    const float* seg32  = (const float*)d_in[6];

    fused_kernel<<<dim3(NBLK_ALL), 256, 0, stream>>>(
        img, heat8, heat16, heat32, seg8, seg16, seg32, (float*)d_out);
}